// Round 1
// baseline (136.231 us; speedup 1.0000x reference)
//
#include <hip/hip_runtime.h>
#include <math.h>

// EUNN layer, H=1024: 16 steps of (even + odd) pairwise complex rotations + final phase.
// v5 = v4 + occupancy doubling. v4 ran R=2 rows/wave -> 2048 waves = 2 waves/SIMD
// (grid-limited; VGPR=124 already allowed 4). Counters: VALUBusy 42%, HBM 13%,
// Occupancy 15% -> latency-bound. v5: R=1 rows/wave -> 4096 waves = 4 blocks/CU
// = 4 waves/SIMD; per-wave VGPR drops (e[] halves), __launch_bounds__(256,4)
// caps allocation at 128 VGPR.
//
// ws layout (f4 units): coeff_t[s][phase][512], slot k = (j&7)*64 + (j>>3) for pair j
//   (phase 0 = even pairs 0..511; phase 1 = odd pairs 0..510 + identity pad 511)
// omega (f4 = 2 elements (c,s,c,s)) transposed the same way at float offset 65536.

typedef float f4 __attribute__((ext_vector_type(4)));

#define OMCS_OFF 65536

__global__ __launch_bounds__(256) void eunn_precompute(
    const float* __restrict__ omega, const float* __restrict__ et,
    const float* __restrict__ ot, const float* __restrict__ ep,
    const float* __restrict__ op, float* __restrict__ ws) {
  int tid = blockIdx.x * 256 + threadIdx.x;
  if (tid < 16384) {
    int s = tid >> 10, k = tid & 1023;
    int phase = k >> 9, j = k & 511;
    float ct, st, cp, sp;
    if (phase == 0) {
      sincosf(et[s * 512 + j], &st, &ct);
      sincosf(ep[s * 512 + j], &sp, &cp);
    } else if (j < 511) {
      sincosf(ot[s * 511 + j], &st, &ct);
      sincosf(op[s * 511 + j], &sp, &cp);
    } else {  // identity pad pair (elements 1023/1024)
      ct = 1.f; st = 0.f; cp = 0.f; sp = 1.f;
    }
    // transposed slot: lane = j>>3 owns pair j as its (j&7)-th register
    ((f4*)ws)[s * 1024 + phase * 512 + (j & 7) * 64 + (j >> 3)] =
        (f4){ct, st, cp, sp};
  } else if (tid < 16896) {
    int m = tid - 16384;  // f4 index covering elements 2m, 2m+1
    float s0, c0, s1, c1;
    sincosf(omega[2 * m], &s0, &c0);
    sincosf(omega[2 * m + 1], &s1, &c1);
    ((f4*)(ws + OMCS_OFF))[(m & 7) * 64 + (m >> 3)] = (f4){c0, s0, c1, s1};
  }
}

// One wave owns R rows; lane l owns elements 16l..16l+15 (8 even pairs).
// Even rotations register-local; odd rotations register-local except one
// boundary pair per lane (intra-wave shfl). Pipeline: O loads issue before
// even compute; next step's E loads issue after even compute.
template <int R>
__global__ __launch_bounds__(256, 4) void eunn_main(
    const float* __restrict__ x, float* __restrict__ out,
    const float* __restrict__ ws) {
  const int lane = threadIdx.x & 63;
  const int wid = blockIdx.x * (blockDim.x >> 6) + (threadIdx.x >> 6);
  const f4* cf = (const f4*)ws + lane;  // + p*64 + s*1024 (+512 for odd)

  // e[r][p] = (re[16l+2p], im[16l+2p], re[16l+2p+1], im[16l+2p+1])
  f4 e[R][8];
#pragma unroll
  for (int r = 0; r < R; ++r) {
    const f4* xr = (const f4*)(x + (size_t)(wid * R + r) * 2048) + lane * 8;
#pragma unroll
    for (int p = 0; p < 8; ++p) e[r][p] = xr[p];
  }

  f4 E[8];  // current step's even coeffs (ct,st,cp,sp per pair)
#pragma unroll
  for (int p = 0; p < 8; ++p) E[p] = cf[p * 64];

#pragma unroll 1
  for (int s = 0; s < 16; ++s) {
    // ---- issue odd coeff loads (completion covered by even compute) ----
    f4 O[8];
    {
      const f4* ob = cf + s * 1024 + 512;
#pragma unroll
      for (int p = 0; p < 8; ++p) O[p] = ob[p * 64];
    }
    // ---- even rotation: pair j=8l+p couples (e.x,e.y) and (e.z,e.w) ----
#pragma unroll
    for (int r = 0; r < R; ++r) {
#pragma unroll
      for (int p = 0; p < 8; ++p) {
        f4 c = E[p];
        f4 v = e[r][p];
        float t0 = c.x * v.x - c.y * v.z;
        float t1 = c.x * v.y - c.y * v.w;
        e[r][p] = (f4){c.w * t0 - c.z * t1, c.z * t0 + c.w * t1,
                       c.y * v.x + c.x * v.z, c.y * v.y + c.x * v.w};
      }
    }
    // ---- load next step's even coeffs into E (covered by odd compute) ----
    {
      const f4* nb = cf + ((s + 1) & 15) * 1024;
#pragma unroll
      for (int p = 0; p < 8; ++p) E[p] = nb[p * 64];
    }
    // ---- odd rotation: pair j couples elements 2j+1, 2j+2 ----
    {
      // neighbor pair (8l-1)'s (ct,st) from lane l-1; identity at lane 0
      float ctm = __shfl_up(O[7].x, 1, 64);
      float stm = __shfl_up(O[7].y, 1, 64);
      if (lane == 0) { ctm = 1.f; stm = 0.f; }
#pragma unroll
      for (int r = 0; r < R; ++r) {
        float upx = __shfl_down(e[r][0].x, 1, 64);  // elem 16l+16 (pre)
        float upy = __shfl_down(e[r][0].y, 1, 64);
        float dnz = __shfl_up(e[r][7].z, 1, 64);    // elem 16l-1 (pre)
        float dnw = __shfl_up(e[r][7].w, 1, 64);
        // element 16l = second half of pair 8l-1
        float nx = stm * dnz + ctm * e[r][0].x;
        float ny = stm * dnw + ctm * e[r][0].y;
        e[r][0].x = nx;
        e[r][0].y = ny;
        // interior odd pairs j=8l+p, p=0..6
#pragma unroll
        for (int p = 0; p < 7; ++p) {
          f4 c = O[p];
          float e0r = e[r][p].z, e0i = e[r][p].w;
          float e1r = e[r][p + 1].x, e1i = e[r][p + 1].y;
          float t0 = c.x * e0r - c.y * e1r;
          float t1 = c.x * e0i - c.y * e1i;
          e[r][p].z = c.w * t0 - c.z * t1;
          e[r][p].w = c.z * t0 + c.w * t1;
          e[r][p + 1].x = c.y * e0r + c.x * e1r;
          e[r][p + 1].y = c.y * e0i + c.x * e1i;
        }
        // boundary pair j=8l+7 (second element lives in lane l+1; lane 63 = identity)
        {
          f4 c = O[7];
          float e0r = e[r][7].z, e0i = e[r][7].w;
          float t0 = c.x * e0r - c.y * upx;
          float t1 = c.x * e0i - c.y * upy;
          e[r][7].z = c.w * t0 - c.z * t1;
          e[r][7].w = c.z * t0 + c.w * t1;
        }
      }
    }
  }

  // ---- final diagonal phase + store ----
  const f4* om4 = (const f4*)(ws + OMCS_OFF) + lane;  // (c,s,c,s), + p*64
#pragma unroll
  for (int r = 0; r < R; ++r) {
    f4* outr = (f4*)(out + (size_t)(wid * R + r) * 2048) + lane * 8;
#pragma unroll
    for (int p = 0; p < 8; ++p) {
      f4 v = e[r][p];
      f4 w = om4[p * 64];
      outr[p] = (f4){v.x * w.x - v.y * w.y, v.x * w.y + v.y * w.x,
                     v.z * w.z - v.w * w.w, v.z * w.w + v.w * w.z};
    }
  }
}

extern "C" void kernel_launch(void* const* d_in, const int* in_sizes, int n_in,
                              void* d_out, int out_size, void* d_ws, size_t ws_size,
                              hipStream_t stream) {
  const float* x     = (const float*)d_in[0];  // (4096,1024,2)
  const float* omega = (const float*)d_in[1];  // (1024,)
  const float* et    = (const float*)d_in[2];  // (16,512)
  const float* ot    = (const float*)d_in[3];  // (16,511)
  const float* ep    = (const float*)d_in[4];  // (16,512)
  const float* op    = (const float*)d_in[5];  // (16,511)
  float* out = (float*)d_out;
  float* ws  = (float*)d_ws;

  // 16896 jobs: 16x1024 coeff quads + 512 omega f4 entries
  eunn_precompute<<<dim3(66), dim3(256), 0, stream>>>(omega, et, ot, ep, op, ws);

  // R=1 row/wave: 4096 waves, 4 waves/block -> 1024 blocks -> 4 blocks/CU
  eunn_main<1><<<dim3(1024), dim3(256), 0, stream>>>(x, out, ws);
}